// Round 1
// baseline (3766.576 us; speedup 1.0000x reference)
//
#include <hip/hip_runtime.h>

#define D   12
#define EPT 4
#define BLK 256

__global__ __launch_bounds__(BLK) void edge_mlp_scatter(
    const float* __restrict__ edges,
    const float* __restrict__ bn_scale,
    const float* __restrict__ bn_bias,
    const float* __restrict__ bn_mean,
    const float* __restrict__ bn_var,
    const float* __restrict__ W1,
    const float* __restrict__ b1,
    const float* __restrict__ W2,
    const float* __restrict__ b2,
    const int* __restrict__ receivers,
    float* __restrict__ out,
    long E)
{
    // Folded weights in LDS: sW1[d][j] = a[d]*W1[d][j]  (BN scale folded in)
    // sB1[j] = b1[j] + sum_d c[d]*W1[d][j]               (BN shift folded in)
    __shared__ float sW1[D * D];
    __shared__ float sW2[D * D];
    __shared__ float sB1[D];
    __shared__ float sB2[D];

    const int t = threadIdx.x;
    if (t < D * D) {
        int d = t / D;
        float a = bn_scale[d] * rsqrtf(bn_var[d] + 1e-5f);
        sW1[t] = a * W1[t];
        sW2[t] = W2[t];
    }
    if (t < D) {
        float acc = b1[t];
        #pragma unroll
        for (int d = 0; d < D; ++d) {
            float a = bn_scale[d] * rsqrtf(bn_var[d] + 1e-5f);
            float c = bn_bias[d] - bn_mean[d] * a;
            acc += c * W1[d * D + t];
        }
        sB1[t] = acc;
        sB2[t] = b2[t];
    }
    __syncthreads();

    const long base = (long)blockIdx.x * (BLK * EPT) + t;

    float x[EPT][D];
    int   rcv[EPT];
    bool  valid[EPT];

    #pragma unroll
    for (int k = 0; k < EPT; ++k) {
        long e = base + (long)k * BLK;
        valid[k] = (e < E);
        rcv[k] = 0;
        if (valid[k]) {
            rcv[k] = receivers[e];
            const float4* p = reinterpret_cast<const float4*>(edges + e * D);
            float4 v0 = p[0], v1 = p[1], v2 = p[2];
            x[k][0] = v0.x; x[k][1] = v0.y; x[k][2]  = v0.z; x[k][3]  = v0.w;
            x[k][4] = v1.x; x[k][5] = v1.y; x[k][6]  = v1.z; x[k][7]  = v1.w;
            x[k][8] = v2.x; x[k][9] = v2.y; x[k][10] = v2.z; x[k][11] = v2.w;
        } else {
            #pragma unroll
            for (int d = 0; d < D; ++d) x[k][d] = 0.f;
        }
    }

    // h = relu(x @ sW1 + sB1); k-inner unroll amortizes each ds_read over EPT FMAs
    float h[EPT][D];
    #pragma unroll
    for (int j = 0; j < D; ++j) {
        float bj = sB1[j];
        #pragma unroll
        for (int k = 0; k < EPT; ++k) h[k][j] = bj;
    }
    #pragma unroll
    for (int d = 0; d < D; ++d) {
        #pragma unroll
        for (int j = 0; j < D; ++j) {
            float w = sW1[d * D + j];
            #pragma unroll
            for (int k = 0; k < EPT; ++k) h[k][j] = fmaf(x[k][d], w, h[k][j]);
        }
    }
    #pragma unroll
    for (int j = 0; j < D; ++j) {
        #pragma unroll
        for (int k = 0; k < EPT; ++k) h[k][j] = fmaxf(h[k][j], 0.f);
    }

    // y = h @ sW2 + sB2, scattered with atomics, one output column at a time
    #pragma unroll
    for (int j = 0; j < D; ++j) {
        float acc[EPT];
        float bj = sB2[j];
        #pragma unroll
        for (int k = 0; k < EPT; ++k) acc[k] = bj;
        #pragma unroll
        for (int d = 0; d < D; ++d) {
            float w = sW2[d * D + j];
            #pragma unroll
            for (int k = 0; k < EPT; ++k) acc[k] = fmaf(h[k][d], w, acc[k]);
        }
        #pragma unroll
        for (int k = 0; k < EPT; ++k) {
            if (valid[k]) atomicAdd(&out[(long)rcv[k] * D + j], acc[k]);
        }
    }
}

extern "C" void kernel_launch(void* const* d_in, const int* in_sizes, int n_in,
                              void* d_out, int out_size, void* d_ws, size_t ws_size,
                              hipStream_t stream) {
    const float* edges     = (const float*)d_in[0];
    const float* bn_scale  = (const float*)d_in[1];
    const float* bn_bias   = (const float*)d_in[2];
    const float* bn_mean   = (const float*)d_in[3];
    const float* bn_var    = (const float*)d_in[4];
    const float* W1        = (const float*)d_in[5];
    const float* b1        = (const float*)d_in[6];
    const float* W2        = (const float*)d_in[7];
    const float* b2        = (const float*)d_in[8];
    const int*   receivers = (const int*)d_in[9];
    float*       out       = (float*)d_out;

    const long E = (long)in_sizes[0] / D;

    // Harness poisons d_out with 0xAA; we accumulate with atomics, so zero it.
    hipMemsetAsync(d_out, 0, (size_t)out_size * sizeof(float), stream);

    const long blocks = (E + (long)(BLK * EPT) - 1) / (long)(BLK * EPT);
    edge_mlp_scatter<<<dim3((unsigned)blocks), dim3(BLK), 0, stream>>>(
        edges, bn_scale, bn_bias, bn_mean, bn_var, W1, b1, W2, b2, receivers, out, E);
}

// Round 3
// 646.566 us; speedup vs baseline: 5.8255x; 5.8255x over previous
//
#include <hip/hip_runtime.h>

#define D    12
#define EPB  4096   // edges per block for passes A/B
#define ABLK 256
#define SBLK 256
#define CBLK 256

// ---------------- pass A: per-block bucket histogram ----------------
__global__ __launch_bounds__(ABLK) void passA_hist(
    const int* __restrict__ receivers, long E, int nbuck,
    int* __restrict__ cnt /* [nblk][nbuck], row-major */)
{
    extern __shared__ int hist[]; // nbuck ints
    for (int i = threadIdx.x; i < nbuck; i += ABLK) hist[i] = 0;
    __syncthreads();
    long e0 = (long)blockIdx.x * EPB;
    long e1 = e0 + EPB; if (e1 > E) e1 = E;
    for (long e = e0 + threadIdx.x; e < e1; e += ABLK) {
        int r = receivers[e];
        atomicAdd(&hist[r >> 7], 1);
    }
    __syncthreads();
    int* row = cnt + (long)blockIdx.x * nbuck;
    for (int i = threadIdx.x; i < nbuck; i += ABLK) row[i] = hist[i];
}

// ---------------- pass S1: exclusive scan down each bucket column ----------------
__global__ __launch_bounds__(SBLK) void passS1_colscan(
    int* __restrict__ cnt, int nblk, int nbuck, int* __restrict__ totals)
{
    int b = blockIdx.x;
    int t = threadIdx.x;
    __shared__ int csum[SBLK];
    int per = (nblk + SBLK - 1) / SBLK;
    int i0 = t * per;
    int i1 = i0 + per; if (i1 > nblk) i1 = nblk;
    int s = 0;
    for (int i = i0; i < i1; ++i) s += cnt[(long)i * nbuck + b];
    csum[t] = s;
    __syncthreads();
    for (int off = 1; off < SBLK; off <<= 1) {
        int add = (t >= off) ? csum[t - off] : 0;
        __syncthreads();
        csum[t] += add;
        __syncthreads();
    }
    int run = csum[t] - s; // exclusive prefix of this thread's chunk
    for (int i = i0; i < i1; ++i) {
        long a = (long)i * nbuck + b;
        int tmp = cnt[a];
        cnt[a] = run;
        run += tmp;
    }
    if (t == SBLK - 1) totals[b] = csum[SBLK - 1];
}

// ---------------- pass S2: exclusive scan over bucket totals ----------------
__global__ __launch_bounds__(1024) void passS2_basescan(
    const int* __restrict__ totals, int* __restrict__ base, int nbuck)
{
    __shared__ int sh[1024];
    int t = threadIdx.x;
    int v = (t < nbuck) ? totals[t] : 0;
    sh[t] = v;
    __syncthreads();
    for (int off = 1; off < 1024; off <<= 1) {
        int add = (t >= off) ? sh[t - off] : 0;
        __syncthreads();
        sh[t] += add;
        __syncthreads();
    }
    if (t < nbuck) base[t] = sh[t] - v;
}

// ---------------- pass B: scatter edge ids into bucket-sorted order ----------------
__global__ __launch_bounds__(ABLK) void passB_scatter(
    const int* __restrict__ receivers, long E, int nbuck,
    const int* __restrict__ cnt, const int* __restrict__ base,
    unsigned int* __restrict__ sorted)
{
    extern __shared__ int cur[]; // nbuck cursors
    const int* row = cnt + (long)blockIdx.x * nbuck;
    for (int i = threadIdx.x; i < nbuck; i += ABLK) cur[i] = row[i] + base[i];
    __syncthreads();
    long e0 = (long)blockIdx.x * EPB;
    long e1 = e0 + EPB; if (e1 > E) e1 = E;
    for (long e = e0 + threadIdx.x; e < e1; e += ABLK) {
        int r = receivers[e];
        int b = r >> 7;
        int pos = atomicAdd(&cur[b], 1);
        sorted[pos] = ((unsigned)e << 7) | (unsigned)(r & 127);
    }
}

// ---------------- pass C: per-bucket gather + fused BN/MLP + LDS reduce ----------------
__global__ __launch_bounds__(CBLK) void passC_gather(
    const float* __restrict__ edges,
    const unsigned int* __restrict__ sorted,
    const int* __restrict__ base, const int* __restrict__ totals,
    const float* __restrict__ bn_scale, const float* __restrict__ bn_bias,
    const float* __restrict__ bn_mean,  const float* __restrict__ bn_var,
    const float* __restrict__ W1, const float* __restrict__ b1,
    const float* __restrict__ W2, const float* __restrict__ b2,
    float* __restrict__ out, int N)
{
    __shared__ float sW1[D * D];
    __shared__ float sW2[D * D];
    __shared__ float sB1[D];
    __shared__ float sB2[D];
    __shared__ float acc[128 * D];

    const int t = threadIdx.x;
    if (t < D * D) {
        int d = t / D;
        float a = bn_scale[d] * rsqrtf(bn_var[d] + 1e-5f);
        sW1[t] = a * W1[t];
        sW2[t] = W2[t];
    }
    if (t < D) {
        float a2 = b1[t];
        #pragma unroll
        for (int d = 0; d < D; ++d) {
            float a = bn_scale[d] * rsqrtf(bn_var[d] + 1e-5f);
            float c = bn_bias[d] - bn_mean[d] * a;
            a2 += c * W1[d * D + t];
        }
        sB1[t] = a2;
        sB2[t] = b2[t];
    }
    for (int i = t; i < 128 * D; i += CBLK) acc[i] = 0.f;
    __syncthreads();

    const int b = blockIdx.x;
    const int s0 = base[b];
    const int n  = totals[b];

    for (int k = t; k < n; k += CBLK) {
        unsigned v = sorted[s0 + k];
        long idx = (long)(v >> 7);
        int rloc = (int)(v & 127u);

        const float4* p = reinterpret_cast<const float4*>(edges + idx * D);
        float4 v0 = p[0], v1 = p[1], v2 = p[2];
        float x[D] = {v0.x, v0.y, v0.z, v0.w, v1.x, v1.y, v1.z, v1.w,
                      v2.x, v2.y, v2.z, v2.w};

        float h[D];
        #pragma unroll
        for (int j = 0; j < D; ++j) h[j] = sB1[j];
        #pragma unroll
        for (int d = 0; d < D; ++d) {
            float xd = x[d];
            #pragma unroll
            for (int j = 0; j < D; ++j) h[j] = fmaf(xd, sW1[d * D + j], h[j]);
        }
        #pragma unroll
        for (int j = 0; j < D; ++j) h[j] = fmaxf(h[j], 0.f);

        float y[D];
        #pragma unroll
        for (int j = 0; j < D; ++j) y[j] = sB2[j];
        #pragma unroll
        for (int d = 0; d < D; ++d) {
            float hd = h[d];
            #pragma unroll
            for (int j = 0; j < D; ++j) y[j] = fmaf(hd, sW2[d * D + j], y[j]);
        }
        #pragma unroll
        for (int j = 0; j < D; ++j) atomicAdd(&acc[rloc * D + j], y[j]);
    }
    __syncthreads();

    long nbase = (long)b * 128;
    int nvalid = N - (int)nbase; if (nvalid > 128) nvalid = 128;
    if (nvalid < 0) nvalid = 0;
    for (int i = t; i < nvalid * D; i += CBLK) out[nbase * D + i] = acc[i];
}

// ---------------- fallback (round-1 kernel) if ws too small ----------------
#define EPT 4
__global__ __launch_bounds__(ABLK) void edge_mlp_scatter(
    const float* __restrict__ edges,
    const float* __restrict__ bn_scale, const float* __restrict__ bn_bias,
    const float* __restrict__ bn_mean,  const float* __restrict__ bn_var,
    const float* __restrict__ W1, const float* __restrict__ b1,
    const float* __restrict__ W2, const float* __restrict__ b2,
    const int* __restrict__ receivers, float* __restrict__ out, long E)
{
    __shared__ float sW1[D * D], sW2[D * D], sB1[D], sB2[D];
    const int t = threadIdx.x;
    if (t < D * D) {
        int d = t / D;
        float a = bn_scale[d] * rsqrtf(bn_var[d] + 1e-5f);
        sW1[t] = a * W1[t];
        sW2[t] = W2[t];
    }
    if (t < D) {
        float a2 = b1[t];
        #pragma unroll
        for (int d = 0; d < D; ++d) {
            float a = bn_scale[d] * rsqrtf(bn_var[d] + 1e-5f);
            float c = bn_bias[d] - bn_mean[d] * a;
            a2 += c * W1[d * D + t];
        }
        sB1[t] = a2; sB2[t] = b2[t];
    }
    __syncthreads();
    const long basee = (long)blockIdx.x * (ABLK * EPT) + t;
    float x[EPT][D]; int rcv[EPT]; bool valid[EPT];
    #pragma unroll
    for (int k = 0; k < EPT; ++k) {
        long e = basee + (long)k * ABLK;
        valid[k] = (e < E); rcv[k] = 0;
        if (valid[k]) {
            rcv[k] = receivers[e];
            const float4* p = reinterpret_cast<const float4*>(edges + e * D);
            float4 v0 = p[0], v1 = p[1], v2 = p[2];
            x[k][0]=v0.x; x[k][1]=v0.y; x[k][2]=v0.z; x[k][3]=v0.w;
            x[k][4]=v1.x; x[k][5]=v1.y; x[k][6]=v1.z; x[k][7]=v1.w;
            x[k][8]=v2.x; x[k][9]=v2.y; x[k][10]=v2.z; x[k][11]=v2.w;
        } else {
            #pragma unroll
            for (int d = 0; d < D; ++d) x[k][d] = 0.f;
        }
    }
    float h[EPT][D];
    #pragma unroll
    for (int j = 0; j < D; ++j) {
        float bj = sB1[j];
        #pragma unroll
        for (int k = 0; k < EPT; ++k) h[k][j] = bj;
    }
    #pragma unroll
    for (int d = 0; d < D; ++d) {
        #pragma unroll
        for (int j = 0; j < D; ++j) {
            float w = sW1[d * D + j];
            #pragma unroll
            for (int k = 0; k < EPT; ++k) h[k][j] = fmaf(x[k][d], w, h[k][j]);
        }
    }
    #pragma unroll
    for (int j = 0; j < D; ++j) {
        #pragma unroll
        for (int k = 0; k < EPT; ++k) h[k][j] = fmaxf(h[k][j], 0.f);
    }
    #pragma unroll
    for (int j = 0; j < D; ++j) {
        float a2[EPT]; float bj = sB2[j];
        #pragma unroll
        for (int k = 0; k < EPT; ++k) a2[k] = bj;
        #pragma unroll
        for (int d = 0; d < D; ++d) {
            float w = sW2[d * D + j];
            #pragma unroll
            for (int k = 0; k < EPT; ++k) a2[k] = fmaf(h[k][d], w, a2[k]);
        }
        #pragma unroll
        for (int k = 0; k < EPT; ++k)
            if (valid[k]) atomicAdd(&out[(long)rcv[k] * D + j], a2[k]);
    }
}

extern "C" void kernel_launch(void* const* d_in, const int* in_sizes, int n_in,
                              void* d_out, int out_size, void* d_ws, size_t ws_size,
                              hipStream_t stream) {
    const float* edges     = (const float*)d_in[0];
    const float* bn_scale  = (const float*)d_in[1];
    const float* bn_bias   = (const float*)d_in[2];
    const float* bn_mean   = (const float*)d_in[3];
    const float* bn_var    = (const float*)d_in[4];
    const float* W1        = (const float*)d_in[5];
    const float* b1        = (const float*)d_in[6];
    const float* W2        = (const float*)d_in[7];
    const float* b2        = (const float*)d_in[8];
    const int*   receivers = (const int*)d_in[9];
    float*       out       = (float*)d_out;

    const long E = (long)in_sizes[0] / D;
    const int  N = out_size / D;

    const int  nbuck = (N + 127) >> 7;
    const long nblk  = (E + EPB - 1) / EPB;
    const size_t cntBytes = (size_t)nblk * (size_t)nbuck * 4u;
    const size_t need = cntBytes + 2u * (size_t)nbuck * 4u + (size_t)E * 4u + 256u;

    if (ws_size < need || nbuck > 1024 || E >= (1L << 23)) {
        // fallback: direct atomic scatter (round-1 path)
        (void)hipMemsetAsync(d_out, 0, (size_t)out_size * sizeof(float), stream);
        const long blocks = (E + (long)(ABLK * EPT) - 1) / (long)(ABLK * EPT);
        edge_mlp_scatter<<<dim3((unsigned)blocks), dim3(ABLK), 0, stream>>>(
            edges, bn_scale, bn_bias, bn_mean, bn_var, W1, b1, W2, b2,
            receivers, out, E);
        return;
    }

    char* w = (char*)d_ws;
    int* cnt    = (int*)w;            w += cntBytes;
    int* totals = (int*)w;            w += (size_t)nbuck * 4u;
    int* basep  = (int*)w;            w += (size_t)nbuck * 4u;
    unsigned int* sorted = (unsigned int*)w;

    const size_t lds = (size_t)nbuck * 4u;

    passA_hist   <<<dim3((unsigned)nblk), dim3(ABLK), lds, stream>>>(receivers, E, nbuck, cnt);
    passS1_colscan<<<dim3((unsigned)nbuck), dim3(SBLK), 0, stream>>>(cnt, (int)nblk, nbuck, totals);
    passS2_basescan<<<dim3(1), dim3(1024), 0, stream>>>(totals, basep, nbuck);
    passB_scatter<<<dim3((unsigned)nblk), dim3(ABLK), lds, stream>>>(receivers, E, nbuck, cnt, basep, sorted);
    passC_gather <<<dim3((unsigned)nbuck), dim3(CBLK), 0, stream>>>(
        edges, sorted, basep, totals,
        bn_scale, bn_bias, bn_mean, bn_var, W1, b1, W2, b2, out, N);
}